// Round 1
// baseline (5940.301 us; speedup 1.0000x reference)
//
#include <hip/hip_runtime.h>
#include <math.h>

#define NTHR 512
#define DD   128

// ---------- packed argmax key: (ordered float)<<32 | ~idx  (ties -> smallest idx, like jnp.argmax)
__device__ __forceinline__ unsigned long long pkkey(float f, unsigned idx) {
  unsigned u = __float_as_uint(f);
  u = (u & 0x80000000u) ? ~u : (u | 0x80000000u);
  return ((unsigned long long)u << 32) | (unsigned long long)(~idx);
}

__device__ __forceinline__ unsigned long long wredmax(unsigned long long v) {
#pragma unroll
  for (int m = 32; m; m >>= 1) {
    unsigned long long o = __shfl_xor(v, m, 64);
    v = (o > v) ? o : v;
  }
  return v;
}

// ---------- device-wide sense-reversing barrier (agent-scope atomics; safe cross-XCD)
__device__ __forceinline__ void gbar(unsigned* cnt, unsigned* gen, unsigned nblk) {
  __syncthreads();
  if (threadIdx.x == 0) {
    unsigned g = __hip_atomic_load(gen, __ATOMIC_RELAXED, __HIP_MEMORY_SCOPE_AGENT);
    unsigned a = __hip_atomic_fetch_add(cnt, 1u, __ATOMIC_ACQ_REL, __HIP_MEMORY_SCOPE_AGENT);
    if (a == nblk - 1u) {
      __hip_atomic_store(cnt, 0u, __ATOMIC_RELAXED, __HIP_MEMORY_SCOPE_AGENT);
      __hip_atomic_store(gen, g + 1u, __ATOMIC_RELEASE, __HIP_MEMORY_SCOPE_AGENT);
    } else {
      while (__hip_atomic_load(gen, __ATOMIC_ACQUIRE, __HIP_MEMORY_SCOPE_AGENT) == g) {
        __builtin_amdgcn_s_sleep(2);
      }
    }
  }
  __syncthreads();
}

// ---------- reduce the per-block partials (all blocks do this redundantly -> uniform result)
__device__ __forceinline__ int redpart(unsigned long long* part, unsigned long long* s_r, int nblk) {
  const int tid = threadIdx.x, lane = tid & 63, wid = tid >> 6;
  unsigned long long v = 0ull;
  if (tid < nblk)
    v = __hip_atomic_load(&part[tid], __ATOMIC_ACQUIRE, __HIP_MEMORY_SCOPE_AGENT);
  v = wredmax(v);
  if (lane == 0 && wid < 4) s_r[wid] = v;
  __syncthreads();
  unsigned long long m = s_r[0];
#pragma unroll
  for (int i = 1; i < 4; ++i) { unsigned long long o = s_r[i]; if (o > m) m = o; }
  return (int)(~(unsigned)m);
}

// ---------- stage normalized selected row into LDS (f32 squares, exact f64 sum, f32 sqrt, IEEE f32 div)
__device__ __forceinline__ void stage(const float* __restrict__ feat, int c,
                                      float* s_sel, float* s_nrm) {
  const int tid = threadIdx.x, lane = tid & 63;
  const float* __restrict__ row = feat + (size_t)c * DD;
  if (tid < 64) {
    float x1 = row[lane], x2 = row[lane + 64];
    double s = (double)(x1 * x1) + (double)(x2 * x2);
#pragma unroll
    for (int m = 32; m; m >>= 1) s += __shfl_xor(s, m, 64);
    if (lane == 0) *s_nrm = fmaxf(sqrtf((float)s), 1e-12f);
  }
  __syncthreads();
  const float nm = *s_nrm;
  if (tid < DD) s_sel[tid] = row[tid] / nm;
  __syncthreads();
}

__device__ __forceinline__ float distTo(const float* p, const float* s_sel) {
  double a0 = 0.0, a1 = 0.0, a2 = 0.0, a3 = 0.0;
#pragma unroll
  for (int j = 0; j < DD; j += 4) {
    float d0 = p[j]     - s_sel[j];
    float d1 = p[j + 1] - s_sel[j + 1];
    float d2 = p[j + 2] - s_sel[j + 2];
    float d3 = p[j + 3] - s_sel[j + 3];
    float q0 = d0 * d0, q1 = d1 * d1, q2 = d2 * d2, q3 = d3 * d3;
    a0 += (double)q0; a1 += (double)q1; a2 += (double)q2; a3 += (double)q3;
  }
  return sqrtf((float)((a0 + a1) + (a2 + a3)));
}

__global__ __launch_bounds__(NTHR, 2)
void fps_kernel(const float* __restrict__ feat, const float* __restrict__ att,
                const int* __restrict__ kptr, int* __restrict__ out,
                unsigned* cnt, unsigned* gen, unsigned long long* partials,
                int N, int nblk) {
  __shared__ unsigned long long s_w[8];
  __shared__ unsigned long long s_r[4];
  __shared__ float s_sel[DD];
  __shared__ float s_nrm;

  const int tid  = threadIdx.x;
  const int wid  = tid >> 6;
  const int lane = tid & 63;
  const int gid  = blockIdx.x * NTHR + tid;
  const int k    = kptr[0];

  if (k >= N) {  // reference returns arange(N)
    for (int i = gid; i < N; i += nblk * NTHR) out[i] = i;
    return;
  }

  // ---- load own point into VGPRs and L2-normalize it
  const float* __restrict__ myrow = feat + (size_t)gid * DD;
  float p[DD];
#pragma unroll
  for (int j = 0; j < DD; j += 4) {
    const float4 v = *reinterpret_cast<const float4*>(myrow + j);
    p[j] = v.x; p[j + 1] = v.y; p[j + 2] = v.z; p[j + 3] = v.w;
  }
  {
    double a0 = 0.0, a1 = 0.0, a2 = 0.0, a3 = 0.0;
#pragma unroll
    for (int j = 0; j < DD; j += 4) {
      float q0 = p[j] * p[j],         q1 = p[j + 1] * p[j + 1];
      float q2 = p[j + 2] * p[j + 2], q3 = p[j + 3] * p[j + 3];
      a0 += (double)q0; a1 += (double)q1; a2 += (double)q2; a3 += (double)q3;
    }
    float nm = fmaxf(sqrtf((float)((a0 + a1) + (a2 + a3))), 1e-12f);
#pragma unroll
    for (int j = 0; j < DD; ++j) p[j] = p[j] / nm;
  }

  // ---- phase A: argmax(attention_scores) -> first index
  {
    unsigned long long key = pkkey(att[gid], (unsigned)gid);
    key = wredmax(key);
    if (lane == 0) s_w[wid] = key;
  }
  __syncthreads();
  if (tid < 64) {
    unsigned long long x = (lane < 8) ? s_w[lane] : 0ull;
    x = wredmax(x);
    if (lane == 0)
      __hip_atomic_store(&partials[blockIdx.x], x, __ATOMIC_RELEASE, __HIP_MEMORY_SCOPE_AGENT);
  }
  gbar(cnt, gen, (unsigned)nblk);
  int far = redpart(partials, s_r, nblk);
  if (gid == 0) out[0] = far;

  // ---- initial distances to first point
  stage(feat, far, s_sel, &s_nrm);
  float mind;
  {
    float d = distTo(p, s_sel);
    mind = (gid == far) ? -__builtin_inff() : d;
  }

  // ---- main FPS loop: argmax(min_d) -> update
  for (int t = 1; t < k; ++t) {
    unsigned long long key = pkkey(mind, (unsigned)gid);
    key = wredmax(key);
    if (lane == 0) s_w[wid] = key;
    __syncthreads();
    if (tid < 64) {
      unsigned long long x = (lane < 8) ? s_w[lane] : 0ull;
      x = wredmax(x);
      if (lane == 0)
        __hip_atomic_store(&partials[(t & 1) * nblk + blockIdx.x], x,
                           __ATOMIC_RELEASE, __HIP_MEMORY_SCOPE_AGENT);
    }
    gbar(cnt, gen, (unsigned)nblk);
    far = redpart(partials + (t & 1) * nblk, s_r, nblk);
    if (gid == 0) out[t] = far;

    stage(feat, far, s_sel, &s_nrm);
    float d = distTo(p, s_sel);
    mind = fminf(mind, d);
    if (gid == far) mind = -__builtin_inff();
  }
}

extern "C" void kernel_launch(void* const* d_in, const int* in_sizes, int n_in,
                              void* d_out, int out_size, void* d_ws, size_t ws_size,
                              hipStream_t stream) {
  const float* feat = (const float*)d_in[0];
  const float* att  = (const float*)d_in[1];
  const int*   kptr = (const int*)d_in[2];
  int* out = (int*)d_out;

  const int N = in_sizes[1];          // 131072; in_sizes[0] = N*128
  const int nblk = N / NTHR;          // 256 blocks -> 1 per CU, all co-resident

  unsigned char* ws = (unsigned char*)d_ws;
  unsigned* cnt = (unsigned*)ws;
  unsigned* gen = (unsigned*)(ws + 128);
  unsigned long long* partials = (unsigned long long*)(ws + 256);

  hipMemsetAsync(d_ws, 0, 256, stream);  // reset barrier state every call (graph-replay safe)
  fps_kernel<<<nblk, NTHR, 0, stream>>>(feat, att, kptr, out, cnt, gen, partials, N, nblk);
}

// Round 2
// 5012.822 us; speedup vs baseline: 1.1850x; 1.1850x over previous
//
#include <hip/hip_runtime.h>
#include <math.h>

#define NTHR 1024   // threads per block (2 threads per point)
#define DD   128    // feature dim
#define HD   64     // dims per thread

typedef unsigned long long ull;

// packed argmax key: (ordered f32)<<32 | ~idx  -> max() gives argmax with
// smallest-index tie-break, matching jnp.argmax first-occurrence.
__device__ __forceinline__ ull pkkey(float f, unsigned idx) {
  unsigned u = __float_as_uint(f);
  u = (u & 0x80000000u) ? ~u : (u | 0x80000000u);
  return ((ull)u << 32) | (ull)(~idx);
}

__device__ __forceinline__ ull wredmax(ull v) {
#pragma unroll
  for (int m = 32; m; m >>= 1) {
    ull o = __shfl_xor(v, m, 64);
    v = (o > v) ? o : v;
  }
  return v;
}

// Fused {block argmax -> tagged slot store -> all-blocks poll -> local reduce}.
// Slot format: f32bits<<32 | (t+1)<<17 | idx   (idx < 2^17, tag 1..k fits 15 bits;
// memset-0 init never matches a tag). Double-buffered by t&1: blocks can be at
// most one phase apart, so a slot is never overwritten while still being polled.
__device__ __forceinline__ int roundSync(float val, unsigned pidx, int t,
                                         ull* __restrict__ partials, int nblk,
                                         ull* s_w, ull* s_r,
                                         int tid, int lane, int wid, int blockId) {
  ull key = wredmax(pkkey(val, pidx));
  if (lane == 0) s_w[wid] = key;
  __syncthreads();
  if (tid == 0) {
    ull m = s_w[0];
#pragma unroll
    for (int i = 1; i < NTHR / 64; ++i) { ull o = s_w[i]; if (o > m) m = o; }
    unsigned idx = ~(unsigned)m;  // low word was ~idx
    ull slotv = (m & 0xFFFFFFFF00000000ull) | ((ull)(unsigned)(t + 1) << 17) | (ull)idx;
    __hip_atomic_store(&partials[(t & 1) * nblk + blockId], slotv,
                       __ATOMIC_RELAXED, __HIP_MEMORY_SCOPE_AGENT);
  }
  // poll all slots in parallel (one per thread) -- no atomic RMW, no serialization
  ull ck = 0;
  if (tid < nblk) {
    ull* slot = &partials[(t & 1) * nblk + tid];
    const unsigned tag = (unsigned)(t + 1);
    ull v;
    do {
      v = __hip_atomic_load(slot, __ATOMIC_ACQUIRE, __HIP_MEMORY_SCOPE_AGENT);
    } while (((unsigned)(v >> 17) & 0x7FFFu) != tag);
    unsigned idx = (unsigned)v & 0x1FFFFu;
    ck = (v & 0xFFFFFFFF00000000ull) | (ull)(~idx);
  }
  ck = wredmax(ck);
  if (lane == 0) s_r[wid] = ck;
  __syncthreads();
  ull m = s_r[0];
#pragma unroll
  for (int i = 1; i < NTHR / 64; ++i) { ull o = s_r[i]; if (o > m) m = o; }
  return (int)(~(unsigned)m);
}

// stage normalized selected row into LDS (f32 squares, exact f64 sum, f32 sqrt, IEEE f32 div)
__device__ __forceinline__ void stage(const float* __restrict__ feat, int c,
                                      float* s_sel, float* s_nrm, int tid, int lane) {
  const float* __restrict__ row = feat + (size_t)c * DD;
  if (tid < 64) {
    float x1 = row[lane], x2 = row[lane + 64];
    double s = (double)(x1 * x1) + (double)(x2 * x2);
#pragma unroll
    for (int m = 32; m; m >>= 1) s += __shfl_xor(s, m, 64);
    if (lane == 0) *s_nrm = fmaxf(sqrtf((float)s), 1e-12f);
  }
  __syncthreads();
  const float nm = *s_nrm;
  if (tid < DD) s_sel[tid] = row[tid] / nm;
  __syncthreads();
}

// distance of my point (half-row in regs) to staged row; pair halves combined via shfl
__device__ __forceinline__ float distTo(const float4* pv, const float* s_sel, int half) {
  const float4* sp = reinterpret_cast<const float4*>(s_sel) + half * (HD / 4);
  double a0 = 0.0, a1 = 0.0, a2 = 0.0, a3 = 0.0;
#pragma unroll
  for (int j = 0; j < HD / 4; ++j) {
    float4 v = pv[j], c = sp[j];
    float d0 = v.x - c.x, d1 = v.y - c.y, d2 = v.z - c.z, d3 = v.w - c.w;
    a0 += (double)(d0 * d0); a1 += (double)(d1 * d1);
    a2 += (double)(d2 * d2); a3 += (double)(d3 * d3);
  }
  double s = (a0 + a1) + (a2 + a3);
  s += __shfl_xor(s, 1, 64);   // combine the pair's halves (exact to ~2^-52)
  return sqrtf((float)s);
}

__global__ __launch_bounds__(NTHR, 4)
void fps_kernel(const float* __restrict__ feat, const float* __restrict__ att,
                const int* __restrict__ kptr, int* __restrict__ out,
                ull* __restrict__ partials, int N, int nblk) {
  __shared__ ull s_w[NTHR / 64];
  __shared__ ull s_r[NTHR / 64];
  __shared__ alignas(16) float s_sel[DD];
  __shared__ float s_nrm;

  const int tid  = threadIdx.x;
  const int lane = tid & 63;
  const int wid  = tid >> 6;
  const int gid  = blockIdx.x * NTHR + tid;
  const int pidx = gid >> 1;   // point index (2 threads per point)
  const int half = tid & 1;    // which 64-dim half this thread owns
  const int k    = kptr[0];

  if (k >= N) {  // reference returns arange(N)
    for (int i = gid; i < N; i += nblk * NTHR) out[i] = i;
    return;
  }

  // ---- load my 64-dim half into VGPRs (perfectly coalesced: addr = gid*64*4B)
  const float* __restrict__ base = feat + (size_t)gid * HD;
  float4 pv[HD / 4];
#pragma unroll
  for (int j = 0; j < HD / 4; ++j) pv[j] = reinterpret_cast<const float4*>(base)[j];

  // ---- L2-normalize (f32 squares, exact f64 sum across both halves)
  {
    double a0 = 0.0, a1 = 0.0, a2 = 0.0, a3 = 0.0;
#pragma unroll
    for (int j = 0; j < HD / 4; ++j) {
      float4 v = pv[j];
      a0 += (double)(v.x * v.x); a1 += (double)(v.y * v.y);
      a2 += (double)(v.z * v.z); a3 += (double)(v.w * v.w);
    }
    double s = (a0 + a1) + (a2 + a3);
    s += __shfl_xor(s, 1, 64);
    float nm = fmaxf(sqrtf((float)s), 1e-12f);
#pragma unroll
    for (int j = 0; j < HD / 4; ++j) {
      pv[j].x /= nm; pv[j].y /= nm; pv[j].z /= nm; pv[j].w /= nm;
    }
  }

  // ---- phase A: argmax(attention_scores)
  int far = roundSync(att[pidx], (unsigned)pidx, 0, partials, nblk,
                      s_w, s_r, tid, lane, wid, blockIdx.x);
  if (gid == 0) out[0] = far;

  stage(feat, far, s_sel, &s_nrm, tid, lane);
  float mind = distTo(pv, s_sel, half);
  if (pidx == far) mind = -__builtin_inff();

  // ---- main FPS loop
  for (int t = 1; t < k; ++t) {
    far = roundSync(mind, (unsigned)pidx, t, partials, nblk,
                    s_w, s_r, tid, lane, wid, blockIdx.x);
    if (gid == 0) out[t] = far;

    stage(feat, far, s_sel, &s_nrm, tid, lane);
    float d = distTo(pv, s_sel, half);
    mind = fminf(mind, d);
    if (pidx == far) mind = -__builtin_inff();
  }
}

extern "C" void kernel_launch(void* const* d_in, const int* in_sizes, int n_in,
                              void* d_out, int out_size, void* d_ws, size_t ws_size,
                              hipStream_t stream) {
  const float* feat = (const float*)d_in[0];
  const float* att  = (const float*)d_in[1];
  const int*   kptr = (const int*)d_in[2];
  int* out = (int*)d_out;

  const int N    = in_sizes[1];        // 131072
  const int nblk = (2 * N) / NTHR;     // 256 blocks -> 1 per CU, all co-resident

  ull* partials = (ull*)d_ws;
  // zero the tagged slots every call (graph-replay determinism; tag>=1 never matches 0)
  hipMemsetAsync(d_ws, 0, (size_t)(2 * nblk * sizeof(ull)), stream);
  fps_kernel<<<nblk, NTHR, 0, stream>>>(feat, att, kptr, out, partials, N, nblk);
}